// Round 4
// baseline (526.273 us; speedup 1.0000x reference)
//
#include <hip/hip_runtime.h>
#include <hip/hip_bf16.h>
#include <stdint.h>

// ---------------------------------------------------------------------------
// UNetAttention: hs(2,4096,1280) fp32; self-attention H=8, D=160; out fp32.
// GEMMs via mfma_f32_16x16x32_bf16; flash attention via mfma_f32_32x32x16_bf16
// with swapped QK^T; P goes through a wave-private swizzled LDS buffer
// (packed b32 writes), row-sum kept in registers.
// ---------------------------------------------------------------------------

using bf16x8 = __attribute__((ext_vector_type(8))) short;  // 8 bf16 in 4 VGPRs
using f32x4  = __attribute__((ext_vector_type(4))) float;  // 16x16 MFMA C/D
using f32x16 = __attribute__((ext_vector_type(16))) float; // 32x32 MFMA C/D

__device__ __forceinline__ short f2bf(float f) {
    union { float f; uint32_t u; } v; v.f = f;
    uint32_t r = v.u + 0x7fffu + ((v.u >> 16) & 1u);   // RNE
    return (short)(r >> 16);
}

// async global->LDS DMA, 16B per lane.  LDS dest = wave-uniform base + lane*16.
__device__ __forceinline__ void async16(const short* g, short* l) {
    __builtin_amdgcn_global_load_lds(
        (const __attribute__((address_space(1))) void*)g,
        (__attribute__((address_space(3))) void*)l, 16, 0, 0);
}

// ---------------------------------------------------------------------------
// hs fp32 -> bf16 (row-major, for DMA-staged QKV GEMM A)
// ---------------------------------------------------------------------------
__global__ __launch_bounds__(256) void cast_hs(
    const float* __restrict__ hs, short* __restrict__ out)
{
    int i = (blockIdx.x * 256 + threadIdx.x) * 4;
    float4 v = *(const float4*)&hs[i];
    short4 s; s.x = f2bf(v.x); s.y = f2bf(v.y); s.z = f2bf(v.z); s.w = f2bf(v.w);
    *(short4*)&out[i] = s;
}

// ---------------------------------------------------------------------------
// Weight transpose+cast: w[k][n] fp32 -> wT[n][k] bf16.
// ---------------------------------------------------------------------------
__global__ __launch_bounds__(256) void transpose_w(
    const float* __restrict__ w0, const float* __restrict__ w1,
    const float* __restrict__ w2, const float* __restrict__ w3,
    short* __restrict__ wqkvT, short* __restrict__ woutT)
{
    __shared__ float tile[32][33];
    int z = blockIdx.z;
    const float* src = (z == 0) ? w0 : (z == 1) ? w1 : (z == 2) ? w2 : w3;
    short* dst = (z == 3) ? woutT : (wqkvT + (long)z * 1280 * 1280);
    int k0 = blockIdx.x * 32, n0 = blockIdx.y * 32;
    int t = threadIdx.x, r = t >> 5, c = t & 31;
#pragma unroll
    for (int i = 0; i < 4; i++)
        tile[r + i * 8][c] = src[(long)(k0 + r + i * 8) * 1280 + n0 + c];
    __syncthreads();
#pragma unroll
    for (int i = 0; i < 4; i++)
        dst[(long)(n0 + r + i * 8) * 1280 + k0 + c] = f2bf(tile[c][r + i * 8]);
}

// ---------------------------------------------------------------------------
// v_h [bh][4096][160] bf16 -> v_t [bh][160][4096] bf16
// ---------------------------------------------------------------------------
__global__ __launch_bounds__(256) void transpose_v(
    const short* __restrict__ v, short* __restrict__ vt)
{
    __shared__ short tile[32][33];
    int s0 = blockIdx.x * 32, d0 = blockIdx.y * 32;
    long bh = blockIdx.z;
    const short* src = v + bh * 4096 * 160;
    short* dst = vt + bh * 160 * 4096;
    int t = threadIdx.x, r = t >> 5, c = t & 31;
#pragma unroll
    for (int i = 0; i < 4; i++)
        tile[r + i * 8][c] = src[(s0 + r + i * 8) * 160 + d0 + c];
    __syncthreads();
#pragma unroll
    for (int i = 0; i < 4; i++)
        dst[(d0 + r + i * 8) * 4096 + s0 + c] = tile[c][r + i * 8];
}

// ---------------------------------------------------------------------------
// 128x128 MFMA GEMM, BK=64, global_load_lds staging, XOR-swizzled LDS.
// MODE 0: QKV epilogue (scatter to q_h/k_h/v_h; q pre-scaled by scale*log2e).
// MODE 1: out-proj epilogue (fp32 + bias).
// ---------------------------------------------------------------------------
template <int MODE>
__global__ __launch_bounds__(256, 3) void gemm_k(
    const short* __restrict__ A, const short* __restrict__ BT,
    short* __restrict__ q_h, short* __restrict__ k_h, short* __restrict__ v_h,
    float* __restrict__ outp, const float* __restrict__ bias)
{
    __shared__ __align__(16) short A_lds[128 * 64];
    __shared__ __align__(16) short B_lds[128 * 64];

    int t = threadIdx.x, wave = t >> 6, lane = t & 63;
    int quad = lane >> 4, l15 = lane & 15, h7 = l15 & 7;
    int wr = wave >> 1, wc = wave & 1;
    int m0 = blockIdx.y * 128, n0 = blockIdx.x * 128;

    f32x4 acc[4][4] = {};

    for (int kt = 0; kt < 1280; kt += 64) {
        __syncthreads();
#pragma unroll
        for (int i = 0; i < 4; i++) {
            int chunk = wave * 4 + i;
            int c = chunk * 64 + lane;
            int row = c >> 3, j = (c & 7) ^ (row & 7);
            async16(A  + (long)(m0 + row) * 1280 + kt + j * 8, A_lds + chunk * 512);
            async16(BT + (long)(n0 + row) * 1280 + kt + j * 8, B_lds + chunk * 512);
        }
        __syncthreads();

#pragma unroll
        for (int dk = 0; dk < 2; dk++) {
            bf16x8 a[4], b[4];
#pragma unroll
            for (int mi = 0; mi < 4; mi++) {
                int row = wr * 64 + mi * 16 + l15;
                a[mi] = *(const bf16x8*)&A_lds[row * 64 + ((dk * 4 + quad) ^ h7) * 8];
            }
#pragma unroll
            for (int ni = 0; ni < 4; ni++) {
                int row = wc * 64 + ni * 16 + l15;
                b[ni] = *(const bf16x8*)&B_lds[row * 64 + ((dk * 4 + quad) ^ h7) * 8];
            }
#pragma unroll
            for (int mi = 0; mi < 4; mi++)
#pragma unroll
                for (int ni = 0; ni < 4; ni++)
                    acc[mi][ni] = __builtin_amdgcn_mfma_f32_16x16x32_bf16(
                        a[mi], b[ni], acc[mi][ni], 0, 0, 0);
        }
    }

    const float SL2E = 0.07905694150420949f * 1.4426950408889634f;
#pragma unroll
    for (int mi = 0; mi < 4; mi++) {
#pragma unroll
        for (int ni = 0; ni < 4; ni++) {
#pragma unroll
            for (int r = 0; r < 4; r++) {
                int gr = m0 + wr * 64 + mi * 16 + quad * 4 + r;
                int gc = n0 + wc * 64 + ni * 16 + l15;
                float val = acc[mi][ni][r];
                if (MODE == 0) {
                    int which = gc / 1280;
                    int c1 = gc - which * 1280;
                    int hh = c1 / 160, d = c1 - hh * 160;
                    int b_ = gr >> 12, s = gr & 4095;
                    long addr = (((long)(b_ * 8 + hh)) * 4096 + s) * 160 + d;
                    if (which == 0) val *= SL2E;   // fold scale*log2e into Q
                    short* dst = (which == 0) ? q_h : (which == 1) ? k_h : v_h;
                    dst[addr] = f2bf(val);
                } else {
                    outp[(long)gr * 1280 + gc] = val + bias[gc];
                }
            }
        }
    }
}

// ---------------------------------------------------------------------------
// Flash attention, 32x32x16 MFMA, swapped QK^T, LDS-staged P.
//
// Wave w owns q-rows w*32..w*32+31; lane's q-row = wave*32 + (lane&31).
// QK^T computed SWAPPED: S' = mfma(A=K_frag, B=Q_frag), so col = lane&31 = q
// (lane-local) and row k = (reg&3)+8*(reg>>2)+4*hi  [verified C/D layout].
// Softmax p = exp2(s-16) in registers; pairs packed with v_cvt_pk_bf16_f32
// and written as ds_write_b32 into a wave-private swizzled Ps row (q-row),
// k-label = C/D row formula.  PV A-frags are plain b128 reads from Ps
// (slot (2ks+hi) ^ (l31&7), same XOR law as the write side), so operand
// k-labels agree by construction on both sides of the MFMA.
// Row-sum l accumulated in a register from the rounded bf16 pairs, folded
// at the end with shfl_xor(32); no ones-row trick, no P cross-lane ops.
//
// K/V staging: swizzled global_load_lds DMA, software-pipelined
// (K prefetched under PV, V under QK+softmax; vmcnt(0)+s_barrier discipline).
// ---------------------------------------------------------------------------
__global__ __launch_bounds__(256, 2) void flash_k(
    const short* __restrict__ q_h, const short* __restrict__ k_h,
    const short* __restrict__ v_t, short* __restrict__ attn_out)
{
    __shared__ __align__(16) short Ks128[64 * 128];  // K d 0..127, swizzled (16 slots, XOR row&7)
    __shared__ __align__(16) short Ks32 [64 * 32];   // K d 128..159, swizzled (4 slots, XOR (row>>1)&3)
    __shared__ __align__(16) short Vs   [160 * 64];  // V^T, swizzled (8 slots, XOR row&7)
    __shared__ __align__(16) short Ps   [128 * 72];  // P[q][k 64], 8 slots XOR (q&7), pad 64->72
    // total 59392 B -> 2 blocks/CU

    int t = threadIdx.x, wave = t >> 6, lane = t & 63;
    int l31 = lane & 31, hi = lane >> 5;
    int qt = blockIdx.x;
    long bh = blockIdx.y;
    int b = (int)(bh >> 3), h = (int)(bh & 7);

    // Q B-frags: lane holds Q[q = wave*32+l31][d = dk*16 + hi*8 + 0..7]
    bf16x8 qf[10];
    {
        const short* qg = q_h + (bh * 4096 + qt * 128 + wave * 32 + l31) * 160;
#pragma unroll
        for (int dk = 0; dk < 10; dk++)
            qf[dk] = *(const bf16x8*)&qg[dk * 16 + hi * 8];
    }

    // per-wave staging: 5 K loads, 5 V loads per call
    auto stageK = [&](int k0) {
        const short* kg = k_h + (bh * 4096 + k0) * 160;
#pragma unroll
        for (int i = 0; i < 4; i++) {          // Ks128: 16 issues of 1KB
            int chunk = wave * 4 + i;
            int c = chunk * 64 + lane;
            int row = c >> 4, j = (c & 15) ^ (row & 7);
            async16(kg + row * 160 + j * 8, Ks128 + chunk * 512);
        }
        {                                       // Ks32: 4 issues (1/wave)
            int row = wave * 16 + (lane >> 2);
            int j = (lane & 3) ^ ((lane >> 3) & 3);   // == (lane&3) ^ (((row&15)>>1)&3)
            async16(kg + row * 160 + 128 + j * 8, Ks32 + wave * 512);
        }
    };
    auto stageV = [&](int k0) {
#pragma unroll
        for (int i = 0; i < 5; i++) {          // Vs rows 0..159: 20 issues
            int chunk = wave * 5 + i;
            int c = chunk * 64 + lane;
            int row = c >> 3, j = (c & 7) ^ (row & 7);
            async16(v_t + (bh * 160 + row) * 4096 + k0 + j * 8, Vs + chunk * 512);
        }
    };

    f32x16 o[5] = {};    // O accumulators: o[ct][reg], d = ct*32+l31
    float lacc = 0.f;    // row-sum partial (own 32-k slice per tile)

    // prologue: K(0)+V(0) in flight; wait only K(0) (own 5 oldest), barrier.
    stageK(0);
    stageV(0);
    asm volatile("s_waitcnt vmcnt(5)" ::: "memory");   // K(0) landed (own)
    asm volatile("s_waitcnt lgkmcnt(0)" ::: "memory");
    __builtin_amdgcn_s_barrier();

    int prow = (wave * 32 + l31) * 72;   // wave-private Ps row (q = l31)

    for (int k0 = 0; k0 < 4096; k0 += 64) {
        // ---- QK^T (swapped) + softmax + packed P writes, per 32-k tile ----
#pragma unroll
        for (int kt = 0; kt < 2; kt++) {
            f32x16 s = {};
            __builtin_amdgcn_s_setprio(1);
#pragma unroll
            for (int dk = 0; dk < 8; dk++) {
                bf16x8 ka = *(const bf16x8*)
                    &Ks128[(kt * 32 + l31) * 128 + (((dk * 2 + hi) ^ (l31 & 7)) * 8)];
                s = __builtin_amdgcn_mfma_f32_32x32x16_bf16(ka, qf[dk], s, 0, 0, 0);
            }
#pragma unroll
            for (int dk = 8; dk < 10; dk++) {
                bf16x8 ka = *(const bf16x8*)
                    &Ks32[(kt * 32 + l31) * 32 + ((((dk - 8) * 2 + hi) ^ ((l31 >> 1) & 3)) * 8)];
                s = __builtin_amdgcn_mfma_f32_32x32x16_bf16(ka, qf[dk], s, 0, 0, 0);
            }
            __builtin_amdgcn_s_setprio(0);

            // p = exp2(s-16); reg -> k = (reg&3)+8*(reg>>2)+4*hi (+kt*32).
            // Pack (k even, k odd) pairs; accumulate l; b32-write to Ps.
#pragma unroll
            for (int rg = 0; rg < 4; rg++) {
#pragma unroll
                for (int c = 0; c < 2; c++) {
                    float va = exp2f(s[rg * 4 + 2 * c]     - 16.f);
                    float vb = exp2f(s[rg * 4 + 2 * c + 1] - 16.f);
                    uint32_t pk;
                    asm("v_cvt_pk_bf16_f32 %0, %1, %2" : "=v"(pk) : "v"(va), "v"(vb));
                    lacc += __uint_as_float(pk << 16)
                          + __uint_as_float(pk & 0xffff0000u);
                    int so = (kt * 4 + rg) ^ (l31 & 7);        // k-slot, swizzled
                    *(uint32_t*)&Ps[prow + so * 8 + 2 * c + 4 * hi] = pk;
                }
            }
        }

        // V(t) landed (only V(t) outstanding); all waves done reading Ks(t)
        asm volatile("s_waitcnt vmcnt(0)" ::: "memory");
        asm volatile("s_waitcnt lgkmcnt(0)" ::: "memory");
        __builtin_amdgcn_s_barrier();                      // B

        if (k0 + 64 < 4096) stageK(k0 + 64);   // lands under PV(t)

        // ---- O += P V ----
        __builtin_amdgcn_s_setprio(1);
#pragma unroll
        for (int ks = 0; ks < 4; ks++) {
            bf16x8 ap = *(const bf16x8*)
                &Ps[prow + (((2 * ks + hi) ^ (l31 & 7)) * 8)];
#pragma unroll
            for (int ct = 0; ct < 5; ct++) {
                int row = ct * 32 + l31;
                bf16x8 bv = *(const bf16x8*)
                    &Vs[row * 64 + (((ks * 2 + hi) ^ (row & 7)) * 8)];
                o[ct] = __builtin_amdgcn_mfma_f32_32x32x16_bf16(ap, bv, o[ct], 0, 0, 0);
            }
        }
        __builtin_amdgcn_s_setprio(0);

        // K(t+1) landed (only K(t+1) outstanding); all waves done with Vs(t)
        asm volatile("s_waitcnt vmcnt(0)" ::: "memory");
        asm volatile("s_waitcnt lgkmcnt(0)" ::: "memory");
        __builtin_amdgcn_s_barrier();                      // E

        if (k0 + 64 < 4096) stageV(k0 + 64);   // lands under QK(t+1)+SM(t+1)
    }

    // ---- epilogue: fold row-sum halves, redistribute inverse, write ----
    float lsum = lacc + __shfl_xor(lacc, 32);
    float inv = 1.0f / lsum;         // valid for q = l31 on every lane
    float iv[16];
#pragma unroll
    for (int r = 0; r < 16; r++)
        iv[r] = __shfl(inv, (r & 3) + 8 * (r >> 2) + 4 * hi);  // lane 0..31 holds q=lane

#pragma unroll
    for (int ct = 0; ct < 5; ct++)
#pragma unroll
        for (int r = 0; r < 16; r++) {
            int crow = (r & 3) + 8 * (r >> 2) + 4 * hi;
            int gr = b * 4096 + qt * 128 + wave * 32 + crow;
            int gc = h * 160 + ct * 32 + l31;
            attn_out[(long)gr * 1280 + gc] = f2bf(o[ct][r] * iv[r]);
        }
}

// ---------------------------------------------------------------------------
// Launch
// ---------------------------------------------------------------------------
extern "C" void kernel_launch(void* const* d_in, const int* in_sizes, int n_in,
                              void* d_out, int out_size, void* d_ws, size_t ws_size,
                              hipStream_t stream)
{
    const float* hs = (const float*)d_in[0];
    const float* wq = (const float*)d_in[1];
    const float* wk = (const float*)d_in[2];
    const float* wv = (const float*)d_in[3];
    const float* wo = (const float*)d_in[4];
    const float* bo = (const float*)d_in[5];
    float* out = (float*)d_out;

    // workspace layout (bytes), ~97 MB total
    char* ws = (char*)d_ws;
    short* wqkvT = (short*)(ws + 0);            // 3840*1280*2 = 9,830,400
    short* woutT = (short*)(ws + 9830400);      // 1280*1280*2 = 3,276,800
    short* q_h   = (short*)(ws + 13107200);     // 16*4096*160*2 = 20,971,520
    short* k_h   = (short*)(ws + 34078720);
    short* v_t   = (short*)(ws + 55050240);     // also hs_bf before transpose_v
    short* v_h   = (short*)(ws + 76021760);     // aliased with attn (disjoint lifetimes)
    short* attn  = v_h;
    short* hs_bf = v_t;   // hs_bf dead before v_t is born

    cast_hs<<<10240, 256, 0, stream>>>(hs, hs_bf);
    transpose_w<<<dim3(40, 40, 4), 256, 0, stream>>>(wq, wk, wv, wo, wqkvT, woutT);
    gemm_k<0><<<dim3(30, 64), 256, 0, stream>>>(hs_bf, wqkvT, q_h, k_h, v_h,
                                                nullptr, nullptr);
    transpose_v<<<dim3(128, 5, 16), 256, 0, stream>>>(v_h, v_t);
    flash_k<<<dim3(32, 16), 256, 0, stream>>>(q_h, k_h, v_t, attn);
    gemm_k<1><<<dim3(10, 64), 256, 0, stream>>>(attn, woutT, nullptr, nullptr,
                                                nullptr, out, bo);
}

// Round 5
// 443.162 us; speedup vs baseline: 1.1875x; 1.1875x over previous
//
#include <hip/hip_runtime.h>
#include <hip/hip_bf16.h>
#include <stdint.h>

// ---------------------------------------------------------------------------
// UNetAttention: hs(2,4096,1280) fp32; self-attention H=8, D=160; out fp32.
// GEMMs via mfma_f32_16x16x32_bf16; flash attention via mfma_f32_32x32x16_bf16
// with swapped QK^T; P goes through a wave-private swizzled LDS buffer
// (stride 128B == 0 mod 32 dwords -> pure-XOR bank law; b64 writes).
// ---------------------------------------------------------------------------

using bf16x8 = __attribute__((ext_vector_type(8))) short;  // 8 bf16 in 4 VGPRs
using f32x4  = __attribute__((ext_vector_type(4))) float;  // 16x16 MFMA C/D
using f32x16 = __attribute__((ext_vector_type(16))) float; // 32x32 MFMA C/D

__device__ __forceinline__ short f2bf(float f) {
    union { float f; uint32_t u; } v; v.f = f;
    uint32_t r = v.u + 0x7fffu + ((v.u >> 16) & 1u);   // RNE
    return (short)(r >> 16);
}

// async global->LDS DMA, 16B per lane.  LDS dest = wave-uniform base + lane*16.
__device__ __forceinline__ void async16(const short* g, short* l) {
    __builtin_amdgcn_global_load_lds(
        (const __attribute__((address_space(1))) void*)g,
        (__attribute__((address_space(3))) void*)l, 16, 0, 0);
}

// ---------------------------------------------------------------------------
// hs fp32 -> bf16 (row-major, for DMA-staged QKV GEMM A)
// ---------------------------------------------------------------------------
__global__ __launch_bounds__(256) void cast_hs(
    const float* __restrict__ hs, short* __restrict__ out)
{
    int i = (blockIdx.x * 256 + threadIdx.x) * 4;
    float4 v = *(const float4*)&hs[i];
    short4 s; s.x = f2bf(v.x); s.y = f2bf(v.y); s.z = f2bf(v.z); s.w = f2bf(v.w);
    *(short4*)&out[i] = s;
}

// ---------------------------------------------------------------------------
// Weight transpose+cast: w[k][n] fp32 -> wT[n][k] bf16.
// ---------------------------------------------------------------------------
__global__ __launch_bounds__(256) void transpose_w(
    const float* __restrict__ w0, const float* __restrict__ w1,
    const float* __restrict__ w2, const float* __restrict__ w3,
    short* __restrict__ wqkvT, short* __restrict__ woutT)
{
    __shared__ float tile[32][33];
    int z = blockIdx.z;
    const float* src = (z == 0) ? w0 : (z == 1) ? w1 : (z == 2) ? w2 : w3;
    short* dst = (z == 3) ? woutT : (wqkvT + (long)z * 1280 * 1280);
    int k0 = blockIdx.x * 32, n0 = blockIdx.y * 32;
    int t = threadIdx.x, r = t >> 5, c = t & 31;
#pragma unroll
    for (int i = 0; i < 4; i++)
        tile[r + i * 8][c] = src[(long)(k0 + r + i * 8) * 1280 + n0 + c];
    __syncthreads();
#pragma unroll
    for (int i = 0; i < 4; i++)
        dst[(long)(n0 + r + i * 8) * 1280 + k0 + c] = f2bf(tile[c][r + i * 8]);
}

// ---------------------------------------------------------------------------
// v_h [bh][4096][160] bf16 -> v_t [bh][160][4096] bf16
// ---------------------------------------------------------------------------
__global__ __launch_bounds__(256) void transpose_v(
    const short* __restrict__ v, short* __restrict__ vt)
{
    __shared__ short tile[32][33];
    int s0 = blockIdx.x * 32, d0 = blockIdx.y * 32;
    long bh = blockIdx.z;
    const short* src = v + bh * 4096 * 160;
    short* dst = vt + bh * 160 * 4096;
    int t = threadIdx.x, r = t >> 5, c = t & 31;
#pragma unroll
    for (int i = 0; i < 4; i++)
        tile[r + i * 8][c] = src[(s0 + r + i * 8) * 160 + d0 + c];
    __syncthreads();
#pragma unroll
    for (int i = 0; i < 4; i++)
        dst[(d0 + r + i * 8) * 4096 + s0 + c] = tile[c][r + i * 8];
}

// ---------------------------------------------------------------------------
// 128x128 MFMA GEMM, BK=64, global_load_lds staging, XOR-swizzled LDS.
// MODE 0: QKV epilogue (scatter to q_h/k_h/v_h; q pre-scaled by scale*log2e).
// MODE 1: out-proj epilogue (fp32 + bias).
// ---------------------------------------------------------------------------
template <int MODE>
__global__ __launch_bounds__(256, 3) void gemm_k(
    const short* __restrict__ A, const short* __restrict__ BT,
    short* __restrict__ q_h, short* __restrict__ k_h, short* __restrict__ v_h,
    float* __restrict__ outp, const float* __restrict__ bias)
{
    __shared__ __align__(16) short A_lds[128 * 64];
    __shared__ __align__(16) short B_lds[128 * 64];

    int t = threadIdx.x, wave = t >> 6, lane = t & 63;
    int quad = lane >> 4, l15 = lane & 15, h7 = l15 & 7;
    int wr = wave >> 1, wc = wave & 1;
    int m0 = blockIdx.y * 128, n0 = blockIdx.x * 128;

    f32x4 acc[4][4] = {};

    for (int kt = 0; kt < 1280; kt += 64) {
        __syncthreads();
#pragma unroll
        for (int i = 0; i < 4; i++) {
            int chunk = wave * 4 + i;
            int c = chunk * 64 + lane;
            int row = c >> 3, j = (c & 7) ^ (row & 7);
            async16(A  + (long)(m0 + row) * 1280 + kt + j * 8, A_lds + chunk * 512);
            async16(BT + (long)(n0 + row) * 1280 + kt + j * 8, B_lds + chunk * 512);
        }
        __syncthreads();

#pragma unroll
        for (int dk = 0; dk < 2; dk++) {
            bf16x8 a[4], b[4];
#pragma unroll
            for (int mi = 0; mi < 4; mi++) {
                int row = wr * 64 + mi * 16 + l15;
                a[mi] = *(const bf16x8*)&A_lds[row * 64 + ((dk * 4 + quad) ^ h7) * 8];
            }
#pragma unroll
            for (int ni = 0; ni < 4; ni++) {
                int row = wc * 64 + ni * 16 + l15;
                b[ni] = *(const bf16x8*)&B_lds[row * 64 + ((dk * 4 + quad) ^ h7) * 8];
            }
#pragma unroll
            for (int mi = 0; mi < 4; mi++)
#pragma unroll
                for (int ni = 0; ni < 4; ni++)
                    acc[mi][ni] = __builtin_amdgcn_mfma_f32_16x16x32_bf16(
                        a[mi], b[ni], acc[mi][ni], 0, 0, 0);
        }
    }

    const float SL2E = 0.07905694150420949f * 1.4426950408889634f;
#pragma unroll
    for (int mi = 0; mi < 4; mi++) {
#pragma unroll
        for (int ni = 0; ni < 4; ni++) {
#pragma unroll
            for (int r = 0; r < 4; r++) {
                int gr = m0 + wr * 64 + mi * 16 + quad * 4 + r;
                int gc = n0 + wc * 64 + ni * 16 + l15;
                float val = acc[mi][ni][r];
                if (MODE == 0) {
                    int which = gc / 1280;
                    int c1 = gc - which * 1280;
                    int hh = c1 / 160, d = c1 - hh * 160;
                    int b_ = gr >> 12, s = gr & 4095;
                    long addr = (((long)(b_ * 8 + hh)) * 4096 + s) * 160 + d;
                    if (which == 0) val *= SL2E;   // fold scale*log2e into Q
                    short* dst = (which == 0) ? q_h : (which == 1) ? k_h : v_h;
                    dst[addr] = f2bf(val);
                } else {
                    outp[(long)gr * 1280 + gc] = val + bias[gc];
                }
            }
        }
    }
}

// ---------------------------------------------------------------------------
// Flash attention, 32x32x16 MFMA, swapped QK^T, LDS-staged P.
//
// Wave w owns q-rows w*32..w*32+31; lane's q-row = wave*32 + (lane&31).
// QK^T computed SWAPPED: S' = mfma(A=K_frag, B=Q_frag), so col = lane&31 = q
// (lane-local) and row k = (reg&3)+8*(reg>>2)+4*hi  [verified C/D layout].
// Softmax p = exp2(s-16) in registers; pairs packed with v_cvt_pk_bf16_f32
// and written as ds_write_b64 into a wave-private Ps row (q-row).
//
// Ps bank law (the round-4 regression fix): row stride = 64 shorts = 128 B
// == 0 mod 32 dwords, so the q-row contributes NOTHING to the bank index.
// 16B slot t = k>>3 lives at physical slot t ^ (q&7):
//   * b64 writes (slot t, half hi): per 16-lane phase lanes q and q+8 share
//     a bank pair -> exactly 2-way (free, m136).
//   * b128 PV reads (slot 2ks+hi): per 8-lane phase q&7 distinct -> XOR is
//     a bank bijection -> conflict-free.
// Same pure-XOR law as K/V tiles (stride 0 mod 128B everywhere).
// Row-sum l accumulated in registers from rounded bf16 pairs, folded at the
// end with shfl_xor(32); no ones-row trick, no P cross-lane ops.
//
// K/V staging: swizzled global_load_lds DMA, software-pipelined
// (K prefetched under PV, V under QK+softmax; vmcnt(0)+s_barrier discipline).
// ---------------------------------------------------------------------------
__global__ __launch_bounds__(256, 2) void flash_k(
    const short* __restrict__ q_h, const short* __restrict__ k_h,
    const short* __restrict__ v_t, short* __restrict__ attn_out)
{
    __shared__ __align__(16) short Ks128[64 * 128];  // K d 0..127, swizzled (16 slots, XOR row&7)
    __shared__ __align__(16) short Ks32 [64 * 32];   // K d 128..159, swizzled (4 slots, XOR (row>>1)&3)
    __shared__ __align__(16) short Vs   [160 * 64];  // V^T, swizzled (8 slots, XOR row&7)
    __shared__ __align__(16) short Ps   [128 * 64];  // P[q][k 64], 8 slots XOR (q&7), stride 128B
    // total 57344 B -> 2 blocks/CU

    int t = threadIdx.x, wave = t >> 6, lane = t & 63;
    int l31 = lane & 31, hi = lane >> 5;
    int qt = blockIdx.x;
    long bh = blockIdx.y;
    int b = (int)(bh >> 3), h = (int)(bh & 7);

    // Q B-frags: lane holds Q[q = wave*32+l31][d = dk*16 + hi*8 + 0..7]
    bf16x8 qf[10];
    {
        const short* qg = q_h + (bh * 4096 + qt * 128 + wave * 32 + l31) * 160;
#pragma unroll
        for (int dk = 0; dk < 10; dk++)
            qf[dk] = *(const bf16x8*)&qg[dk * 16 + hi * 8];
    }

    // per-wave staging: 5 K loads, 5 V loads per call
    auto stageK = [&](int k0) {
        const short* kg = k_h + (bh * 4096 + k0) * 160;
#pragma unroll
        for (int i = 0; i < 4; i++) {          // Ks128: 16 issues of 1KB
            int chunk = wave * 4 + i;
            int c = chunk * 64 + lane;
            int row = c >> 4, j = (c & 15) ^ (row & 7);
            async16(kg + row * 160 + j * 8, Ks128 + chunk * 512);
        }
        {                                       // Ks32: 4 issues (1/wave)
            int row = wave * 16 + (lane >> 2);
            int j = (lane & 3) ^ ((lane >> 3) & 3);   // == (lane&3) ^ (((row&15)>>1)&3)
            async16(kg + row * 160 + 128 + j * 8, Ks32 + wave * 512);
        }
    };
    auto stageV = [&](int k0) {
#pragma unroll
        for (int i = 0; i < 5; i++) {          // Vs rows 0..159: 20 issues
            int chunk = wave * 5 + i;
            int c = chunk * 64 + lane;
            int row = c >> 3, j = (c & 7) ^ (row & 7);
            async16(v_t + (bh * 160 + row) * 4096 + k0 + j * 8, Vs + chunk * 512);
        }
    };

    f32x16 o[5] = {};    // O accumulators: o[ct][reg], d = ct*32+l31
    float lacc = 0.f;    // row-sum partial (own 32-k slice per tile)

    // prologue: K(0)+V(0) in flight; wait only K(0) (own 5 oldest), barrier.
    stageK(0);
    stageV(0);
    asm volatile("s_waitcnt vmcnt(5)" ::: "memory");   // K(0) landed (own)
    asm volatile("s_waitcnt lgkmcnt(0)" ::: "memory");
    __builtin_amdgcn_s_barrier();

    int prow = (wave * 32 + l31) * 64;   // wave-private Ps row (q = l31)

    for (int k0 = 0; k0 < 4096; k0 += 64) {
        // ---- QK^T (swapped) + softmax + packed P writes, per 32-k tile ----
#pragma unroll
        for (int kt = 0; kt < 2; kt++) {
            f32x16 s = {};
            __builtin_amdgcn_s_setprio(1);
#pragma unroll
            for (int dk = 0; dk < 8; dk++) {
                bf16x8 ka = *(const bf16x8*)
                    &Ks128[(kt * 32 + l31) * 128 + (((dk * 2 + hi) ^ (l31 & 7)) * 8)];
                s = __builtin_amdgcn_mfma_f32_32x32x16_bf16(ka, qf[dk], s, 0, 0, 0);
            }
#pragma unroll
            for (int dk = 8; dk < 10; dk++) {
                bf16x8 ka = *(const bf16x8*)
                    &Ks32[(kt * 32 + l31) * 32 + ((((dk - 8) * 2 + hi) ^ ((l31 >> 1) & 3)) * 8)];
                s = __builtin_amdgcn_mfma_f32_32x32x16_bf16(ka, qf[dk], s, 0, 0, 0);
            }
            __builtin_amdgcn_s_setprio(0);

            // p = exp2(s-16); reg -> k = (reg&3)+8*(reg>>2)+4*hi (+kt*32).
            // Per rg: pack two (even,odd) pairs, accumulate l, ONE b64 write
            // to slot (kt*4+rg)^(q&7), half hi.
#pragma unroll
            for (int rg = 0; rg < 4; rg++) {
                float va = exp2f(s[rg * 4 + 0] - 16.f);
                float vb = exp2f(s[rg * 4 + 1] - 16.f);
                float vc = exp2f(s[rg * 4 + 2] - 16.f);
                float vd = exp2f(s[rg * 4 + 3] - 16.f);
                uint32_t pk0, pk1;
                asm("v_cvt_pk_bf16_f32 %0, %1, %2" : "=v"(pk0) : "v"(va), "v"(vb));
                asm("v_cvt_pk_bf16_f32 %0, %1, %2" : "=v"(pk1) : "v"(vc), "v"(vd));
                lacc += __uint_as_float(pk0 << 16)
                      + __uint_as_float(pk0 & 0xffff0000u)
                      + __uint_as_float(pk1 << 16)
                      + __uint_as_float(pk1 & 0xffff0000u);
                int so = (kt * 4 + rg) ^ (l31 & 7);        // k-slot, swizzled
                uint2 w; w.x = pk0; w.y = pk1;
                *(uint2*)&Ps[prow + so * 8 + 4 * hi] = w;
            }
        }

        // V(t) landed (only V(t) outstanding); all waves done reading Ks(t)
        asm volatile("s_waitcnt vmcnt(0)" ::: "memory");
        asm volatile("s_waitcnt lgkmcnt(0)" ::: "memory");
        __builtin_amdgcn_s_barrier();                      // B

        if (k0 + 64 < 4096) stageK(k0 + 64);   // lands under PV(t)

        // ---- O += P V ----
        __builtin_amdgcn_s_setprio(1);
#pragma unroll
        for (int ks = 0; ks < 4; ks++) {
            bf16x8 ap = *(const bf16x8*)
                &Ps[prow + (((2 * ks + hi) ^ (l31 & 7)) * 8)];
#pragma unroll
            for (int ct = 0; ct < 5; ct++) {
                int row = ct * 32 + l31;
                bf16x8 bv = *(const bf16x8*)
                    &Vs[row * 64 + (((ks * 2 + hi) ^ (row & 7)) * 8)];
                o[ct] = __builtin_amdgcn_mfma_f32_32x32x16_bf16(ap, bv, o[ct], 0, 0, 0);
            }
        }
        __builtin_amdgcn_s_setprio(0);

        // K(t+1) landed (only K(t+1) outstanding); all waves done with Vs(t)
        asm volatile("s_waitcnt vmcnt(0)" ::: "memory");
        asm volatile("s_waitcnt lgkmcnt(0)" ::: "memory");
        __builtin_amdgcn_s_barrier();                      // E

        if (k0 + 64 < 4096) stageV(k0 + 64);   // lands under QK(t+1)+SM(t+1)
    }

    // ---- epilogue: fold row-sum halves, redistribute inverse, write ----
    float lsum = lacc + __shfl_xor(lacc, 32);
    float inv = 1.0f / lsum;         // valid for q = l31 on every lane
    float iv[16];
#pragma unroll
    for (int r = 0; r < 16; r++)
        iv[r] = __shfl(inv, (r & 3) + 8 * (r >> 2) + 4 * hi);  // lane 0..31 holds q=lane

#pragma unroll
    for (int ct = 0; ct < 5; ct++)
#pragma unroll
        for (int r = 0; r < 16; r++) {
            int crow = (r & 3) + 8 * (r >> 2) + 4 * hi;
            int gr = b * 4096 + qt * 128 + wave * 32 + crow;
            int gc = h * 160 + ct * 32 + l31;
            attn_out[(long)gr * 1280 + gc] = f2bf(o[ct][r] * iv[r]);
        }
}

// ---------------------------------------------------------------------------
// Launch
// ---------------------------------------------------------------------------
extern "C" void kernel_launch(void* const* d_in, const int* in_sizes, int n_in,
                              void* d_out, int out_size, void* d_ws, size_t ws_size,
                              hipStream_t stream)
{
    const float* hs = (const float*)d_in[0];
    const float* wq = (const float*)d_in[1];
    const float* wk = (const float*)d_in[2];
    const float* wv = (const float*)d_in[3];
    const float* wo = (const float*)d_in[4];
    const float* bo = (const float*)d_in[5];
    float* out = (float*)d_out;

    // workspace layout (bytes), ~97 MB total
    char* ws = (char*)d_ws;
    short* wqkvT = (short*)(ws + 0);            // 3840*1280*2 = 9,830,400
    short* woutT = (short*)(ws + 9830400);      // 1280*1280*2 = 3,276,800
    short* q_h   = (short*)(ws + 13107200);     // 16*4096*160*2 = 20,971,520
    short* k_h   = (short*)(ws + 34078720);
    short* v_t   = (short*)(ws + 55050240);     // also hs_bf before transpose_v
    short* v_h   = (short*)(ws + 76021760);     // aliased with attn (disjoint lifetimes)
    short* attn  = v_h;
    short* hs_bf = v_t;   // hs_bf dead before v_t is born

    cast_hs<<<10240, 256, 0, stream>>>(hs, hs_bf);
    transpose_w<<<dim3(40, 40, 4), 256, 0, stream>>>(wq, wk, wv, wo, wqkvT, woutT);
    gemm_k<0><<<dim3(30, 64), 256, 0, stream>>>(hs_bf, wqkvT, q_h, k_h, v_h,
                                                nullptr, nullptr);
    transpose_v<<<dim3(128, 5, 16), 256, 0, stream>>>(v_h, v_t);
    flash_k<<<dim3(32, 16), 256, 0, stream>>>(q_h, k_h, v_t, attn);
    gemm_k<1><<<dim3(10, 64), 256, 0, stream>>>(attn, woutT, nullptr, nullptr,
                                                nullptr, out, bo);
}